// Round 4
// baseline (601.670 us; speedup 1.0000x reference)
//
#include <hip/hip_runtime.h>

// TopKActivation: per row, out = relu(x) masked to its top-128 values.
// R3 (resubmit; prior round hit GPU-acquisition timeout): 4 rows/block,
// register double-buffered prefetch (next row's global loads in flight under
// current row's select); select = one 2048-bin radix pass + candidate
// compaction + exact small-select (value desc, index asc == jax.lax.top_k
// tie semantics). R2's 3-pass radix kept as cnt>CAP fallback. Nontemporal
// vectorized output stores.

constexpr int COLS = 8192;
constexpr int NT   = 256;             // 4 waves
constexpr int V4   = COLS / 4 / NT;   // 8 uint4 (32 values) per thread
constexpr int TOPK = 128;
constexpr int ROWS = 4;               // rows per block
constexpr int CAP  = 1024;            // compaction capacity (fast path)
constexpr int HPAD = 2048 + 2048 / 8; // padded hist words

typedef float v4f __attribute__((ext_vector_type(4)));

__device__ __forceinline__ unsigned hpad(unsigned d) { return d + (d >> 3); }

struct Shared {
  unsigned hist[HPAD];                // 9216 B
  unsigned wtot[4];
  unsigned bc[4];
  unsigned ccount;
  unsigned sres[2];
  unsigned tiectr;
  unsigned long long ckey[CAP];       // 8192 B
};                                    // ~17.5 KiB total

// One radix pass over register-resident values (R2-proven).
template<int SHIFT, int NB, bool FIRST>
__device__ __forceinline__ void radix_pass(
    const uint4 (&va)[V4], unsigned pref, unsigned krem,
    Shared& sh, int tid, int lane, int wv,
    unsigned& sel, unsigned& krem_out, unsigned& cnt_out, unsigned& total_out)
{
  constexpr int LB = (NB == 2048) ? 11 : 10;
  constexpr int BP = NB / NT;

  for (int i = tid; i < NB + NB / 8; i += NT) sh.hist[i] = 0u;
  if (FIRST && tid == 0) sh.ccount = 0u;   // folded clear for compaction
  __syncthreads();

#pragma unroll
  for (int it = 0; it < V4; ++it) {
    unsigned b[4] = {va[it].x, va[it].y, va[it].z, va[it].w};
#pragma unroll
    for (int c = 0; c < 4; ++c) {
      unsigned v = b[c];
      bool ok = FIRST ? (v != 0u) : (v != 0u && (v >> (SHIFT + LB)) == pref);
      if (ok) atomicAdd(&sh.hist[hpad((v >> SHIFT) & (NB - 1))], 1u);
    }
  }
  __syncthreads();

  // hierarchical inclusive suffix scan: thread bins -> wave shfl -> cross-wave
  unsigned h[BP], tot = 0;
#pragma unroll
  for (int i = 0; i < BP; ++i) { h[i] = sh.hist[hpad((unsigned)(tid * BP + i))]; tot += h[i]; }

  unsigned s = tot;
#pragma unroll
  for (int off = 1; off < 64; off <<= 1) {
    unsigned o = __shfl_down(s, off);
    if (lane + off < 64) s += o;
  }
  if (lane == 0) sh.wtot[wv] = s;
  __syncthreads();

  unsigned after = 0;
#pragma unroll
  for (int w = 0; w < 4; ++w) if (w > wv) after += sh.wtot[w];
  const unsigned S_after = (s - tot) + after;

  if (FIRST && tid == 0) sh.bc[3] = s + after;   // total nonzero count

  if (S_after < krem && krem <= S_after + tot) { // unique crossing thread
    unsigned S = S_after;
#pragma unroll
    for (int i = BP - 1; i >= 0; --i) {
      unsigned Sn = S + h[i];
      if (S < krem && krem <= Sn) {
        sh.bc[0] = (unsigned)(tid * BP + i);
        sh.bc[1] = krem - S;
        sh.bc[2] = h[i];
      }
      S = Sn;
    }
  }
  __syncthreads();
  sel      = sh.bc[0];
  krem_out = sh.bc[1];
  cnt_out  = sh.bc[2];
  total_out = FIRST ? sh.bc[3] : 0u;
  // no trailing barrier: next LDS writes (hist clear / ckey) are >=2 barriers out
}

__device__ __forceinline__ void issue_row(uint4 (&buf)[V4],
                                          const uint4* __restrict__ src, int tid) {
#pragma unroll
  for (int it = 0; it < V4; ++it) buf[it] = src[it * NT + tid];
}

__device__ __forceinline__ void select_and_write(
    uint4 (&va)[V4], float* __restrict__ orow, Shared& sh,
    int tid, int lane, int wv)
{
  // relu in place (first use of va -> compiler waits here, prefetch stays out)
#pragma unroll
  for (int it = 0; it < V4; ++it) {
    va[it].x = ((int)va[it].x < 0) ? 0u : va[it].x;
    va[it].y = ((int)va[it].y < 0) ? 0u : va[it].y;
    va[it].z = ((int)va[it].z < 0) ? 0u : va[it].z;
    va[it].w = ((int)va[it].w < 0) ? 0u : va[it].w;
  }

  unsigned sel, krem = TOPK, cnt = 0, total = 0;
  radix_pass<20, 2048, true>(va, 0u, krem, sh, tid, lane, wv, sel, krem, cnt, total);

  unsigned tbits = 0u, C = COLS;       // defaults: keep all positives
  if (total >= TOPK) {                 // uniform branch
    if (cnt <= CAP) {
      // ---- fast path: compact bin==sel candidates, exact rank select ----
#pragma unroll
      for (int it = 0; it < V4; ++it) {
        unsigned b[4] = {va[it].x, va[it].y, va[it].z, va[it].w};
#pragma unroll
        for (int c = 0; c < 4; ++c) {
          unsigned v = b[c];
          bool ok = (v != 0u) && ((v >> 20) == sel);
          if (__any(ok)) {             // skip wave-empty slots (most)
            if (ok) {
              unsigned p = atomicAdd(&sh.ccount, 1u);
              unsigned idx = (unsigned)((it * NT + tid) * 4 + c);
              // key: value desc primary, index asc secondary (unique)
              sh.ckey[p] = ((unsigned long long)v << 13) | (8191u - idx);
            }
          }
        }
      }
      __syncthreads();
      const unsigned n = sh.ccount;    // == cnt <= CAP
      for (unsigned i = tid; i < n; i += NT) {
        unsigned long long ki = sh.ckey[i];
        unsigned r = 0;
        for (unsigned j = 0; j < n; ++j) r += (sh.ckey[j] > ki) ? 1u : 0u;
        if (r == krem - 1) {           // last kept element
          sh.sres[0] = (unsigned)(ki >> 13);
          sh.sres[1] = 8192u - (unsigned)(ki & 0x1FFFu);  // its idx + 1
        }
      }
      __syncthreads();
      tbits = sh.sres[0];
      C = sh.sres[1];
    } else {
      // ---- fallback (never on Gaussian data): R2's exact 3-pass radix ----
      unsigned pref = sel;
      radix_pass<10, 1024, false>(va, pref, krem, sh, tid, lane, wv, sel, krem, cnt, total);
      pref = (pref << 10) | sel;
      radix_pass<0, 1024, false>(va, pref, krem, sh, tid, lane, wv, sel, krem, cnt, total);
      tbits = (pref << 10) | sel;
      if (cnt > krem) {                // exact lowest-index tie-break
        unsigned eq = 0u;
#pragma unroll
        for (int it = 0; it < V4; ++it) {
          if (va[it].x == tbits) eq |= 1u << (it * 4 + 0);
          if (va[it].y == tbits) eq |= 1u << (it * 4 + 1);
          if (va[it].z == tbits) eq |= 1u << (it * 4 + 2);
          if (va[it].w == tbits) eq |= 1u << (it * 4 + 3);
        }
        unsigned lo = 0, hi = COLS;
        while (lo < hi) {
          unsigned mid = (lo + hi) >> 1;
          if (tid == 0) sh.tiectr = 0u;
          __syncthreads();
          if (eq) {
            unsigned c2 = 0;
#pragma unroll
            for (int it = 0; it < V4; ++it)
#pragma unroll
              for (int cc = 0; cc < 4; ++cc)
                if (((eq >> (it * 4 + cc)) & 1u) &&
                    (unsigned)((it * NT + tid) * 4 + cc) < mid) ++c2;
            if (c2) atomicAdd(&sh.tiectr, c2);
          }
          __syncthreads();
          unsigned cm = sh.tiectr;
          if (cm >= krem) hi = mid; else lo = mid + 1;
          __syncthreads();
        }
        C = lo;
      }
    }
  }

  // ---- write from registers; nontemporal (write-once output) ----
  v4f* o4 = reinterpret_cast<v4f*>(orow);
#pragma unroll
  for (int it = 0; it < V4; ++it) {
    unsigned base = (unsigned)(it * NT + tid) * 4u;
    uint4 u = va[it];
    v4f f;
    f.x = (u.x > tbits || (u.x == tbits && base + 0 < C)) ? __uint_as_float(u.x) : 0.0f;
    f.y = (u.y > tbits || (u.y == tbits && base + 1 < C)) ? __uint_as_float(u.y) : 0.0f;
    f.z = (u.z > tbits || (u.z == tbits && base + 2 < C)) ? __uint_as_float(u.z) : 0.0f;
    f.w = (u.w > tbits || (u.w == tbits && base + 3 < C)) ? __uint_as_float(u.w) : 0.0f;
    __builtin_nontemporal_store(f, &o4[it * NT + tid]);
  }
}

__global__ __launch_bounds__(NT, 4)
void topk_relu_kernel(const float* __restrict__ x, float* __restrict__ out)
{
  __shared__ Shared sh;
  const int tid = threadIdx.x, lane = tid & 63, wv = tid >> 6;
  const size_t r0 = (size_t)blockIdx.x * ROWS;

  const uint4* __restrict__ xin = reinterpret_cast<const uint4*>(x) + r0 * (COLS / 4);
  float* __restrict__ orow = out + r0 * COLS;

  uint4 A[V4], B[V4];
  // 1-row-ahead register prefetch pipeline (fully unrolled, static indexing)
  issue_row(A, xin, tid);
  issue_row(B, xin + (COLS / 4), tid);
  select_and_write(A, orow, sh, tid, lane, wv);             // row 0 (row 1 in flight)
  issue_row(A, xin + 2 * (COLS / 4), tid);
  select_and_write(B, orow + COLS, sh, tid, lane, wv);      // row 1 (row 2 in flight)
  issue_row(B, xin + 3 * (COLS / 4), tid);
  select_and_write(A, orow + 2 * COLS, sh, tid, lane, wv);  // row 2 (row 3 in flight)
  select_and_write(B, orow + 3 * COLS, sh, tid, lane, wv);  // row 3
}

extern "C" void kernel_launch(void* const* d_in, const int* in_sizes, int n_in,
                              void* d_out, int out_size, void* d_ws, size_t ws_size,
                              hipStream_t stream) {
  const float* x = (const float*)d_in[0];
  float* out = (float*)d_out;
  const int rows = in_sizes[0] / COLS;       // 8192
  topk_relu_kernel<<<rows / ROWS, NT, 0, stream>>>(x, out);
}